// Round 10
// baseline (15773.648 us; speedup 1.0000x reference)
//
#include <hip/hip_runtime.h>
#include <hip/hip_bf16.h>

typedef __bf16 bf16;
typedef __bf16 bf16x8 __attribute__((ext_vector_type(8)));
typedef float  f32x4  __attribute__((ext_vector_type(4)));

#define AS1 __attribute__((address_space(1)))
#define AS3 __attribute__((address_space(3)))

#define NT   600
#define NB   128
#define NS   512
#define NU   96
#define NK   10
#define NC   80
#define NOUT 121
#define NR   8      // batch rows per m-group (16 groups x 8 rows = 128)

// packed-weight element offsets in ws (bf16 elements), layout [slab][kb][lane][8]
#define W1X_J 0
#define W1W_J 16384
#define W1H_J 65536
#define W1X_K 327680
#define W1W_K 344064
#define W1H_K 393216
#define W2X_J 655360
#define W2W_J 671744
#define W2A_J 720896
#define W2H_J 983040
#define W2X_K 1245184
#define W2W_K 1261568
#define W2A_K 1310720
#define W2H_K 1572864
#define WWIN  1835008
#define WLIN  1851392

#define BIAS_BYTE_OFF 3833856         // 2048 floats: [b1j|b1k|b2j|b2k]
#define H_BYTE_OFF    3842048         // h1[2][128][512], h2..., h3... bf16
#define HBUF 65536                    // bf16 elements per parity buffer
#define FLAG_BYTE_OFF 4659200         // int isF32
#define BAR_BYTE_OFF  4659264         // int bar[1024]; per group m*64: cnt@0 ep@8 dcnt@16 dep@24 xmask@32

#define HSTRIDE 520                   // LDS h-tile row stride in bf16 (1040B: 16B-aligned, bank skew)

// cache-policy aux for global_load_lds (gfx940+ CPol): SC0=bit0, SC1=bit4
#define AUX_SC0   1
#define AUX_SC0S1 17

__device__ __forceinline__ float ldIn(const void* q, long i, int isF32) {
  if (isF32) return ((const float*)q)[i];
  return (float)((const bf16*)q)[i];
}

struct KParams {
  const void* x;       // [128][600][3]
  const void* c_vec;   // [128][96][80]
  const void* b_win;   // [30]
  const void* b_lin;   // [121]
  const bf16* W;       // packed weights base
  const float* bias;   // [4*512]
  bf16* h1; bf16* h2; bf16* h3;  // [2][128][512] each
  void* out;           // [128*600][121]
  const int* flag;
  int* bar;
};

// ---- async global->LDS tile stage: 8 rows x 512 bf16, one 1KB DMA per row ----
template <int AUX>
__device__ __forceinline__ void stage_tile_async(const bf16* g, bf16* lds, int tid) {
  const int w = tid >> 6, lane = tid & 63;
#pragma unroll
  for (int r = 0; r < 2; ++r) {
    const int row = (w << 1) + r;   // 0..7
    __builtin_amdgcn_global_load_lds(
        (const AS1 void*)(g + (size_t)row * NS + (size_t)lane * 8),
        (AS3 void*)(lds + (size_t)row * HSTRIDE), 16, 0, AUX);
  }
}

// ---- central-counter group barrier (proven), split arrive/wait ----
__device__ __forceinline__ void group_arrive(int* gb) {
  __syncthreads();   // drains this WG's h stores before the arrive
  if (threadIdx.x == 0) {
    if ((__hip_atomic_fetch_add(gb, 1, __ATOMIC_RELAXED, __HIP_MEMORY_SCOPE_AGENT) & 31) == 31)
      __hip_atomic_fetch_add(gb + 8, 1, __ATOMIC_RELAXED, __HIP_MEMORY_SCOPE_AGENT);
  }
}
__device__ __forceinline__ void group_wait(int* gb, int target) {
  if (threadIdx.x == 0) {
    while (__hip_atomic_load(gb + 8, __ATOMIC_RELAXED, __HIP_MEMORY_SCOPE_AGENT) < target)
      __builtin_amdgcn_s_sleep(1);
  }
  __syncthreads();
  __atomic_signal_fence(__ATOMIC_ACQ_REL);
}

__device__ __forceinline__ void storeH(unsigned* dst, unsigned v, bool fast) {
  if (fast) *dst = v;   // plain store -> local L2 (same-XCD consumers read with sc0)
  else __hip_atomic_store(dst, v, __ATOMIC_RELAXED, __HIP_MEMORY_SCOPE_AGENT);
}

// ---------------- sniff: decide f32 vs bf16 input encoding ----------------
__global__ void sniff_kernel(const unsigned short* w, int* flag) {
  __shared__ int cnt;
  if (threadIdx.x == 0) cnt = 0;
  __syncthreads();
  int c = 0;
  for (int i = threadIdx.x; i < 8192; i += 256) {
    unsigned e = (w[2 * i] >> 7) & 0xFF;
    if (e == 0xFF || e < 96) c++;
  }
  atomicAdd(&cnt, c);
  __syncthreads();
  if (threadIdx.x == 0) *flag = (cnt > 512) ? 1 : 0;
}

// ---------------- prep: repack weights + zero state + zero barriers ----------------
__global__ void prep_kernel(const void* Wjx1, const void* Wjh1, const void* Wkx1, const void* Wkh1,
                            const void* Wjx2, const void* Wjh2, const void* Wkx2, const void* Wkh2,
                            const void* Wwin, const void* Wlin,
                            const void* bjx1, const void* bjh1, const void* bkx1, const void* bkh1,
                            const void* bjx2, const void* bjh2, const void* bkx2, const void* bkh2,
                            bf16* W, float* bias,
                            bf16* h1, bf16* h2, bf16* h3, int* bar,
                            const int* flag) {
  const int isF32 = *flag;
  const int r = blockIdx.y;
  const int e = blockIdx.x * 256 + threadIdx.x;
  if (r == 16) {
    if (e < 512) {
      bias[e]        = ldIn(bjx1, e, isF32) + ldIn(bjh1, e, isF32);
      bias[512 + e]  = ldIn(bkx1, e, isF32) + ldIn(bkh1, e, isF32);
      bias[1024 + e] = ldIn(bjx2, e, isF32) + ldIn(bjh2, e, isF32);
      bias[1536 + e] = ldIn(bkx2, e, isF32) + ldIn(bkh2, e, isF32);
    }
    return;
  }
  if (r == 17) {
    if (e < HBUF) {   // zero BOTH parities (pipelined schedule consumes zeros from each)
      h1[e] = (bf16)0.f; h1[HBUF + e] = (bf16)0.f;
      h2[e] = (bf16)0.f; h2[HBUF + e] = (bf16)0.f;
      h3[e] = (bf16)0.f; h3[HBUF + e] = (bf16)0.f;
    }
    if (e < 1024) bar[e] = 0;
    return;
  }
  const int   row0s[16]  = {0,3,0, 0,3,0, 0,515,3,0, 0,515,3,0, 0,0};
  const int   klens[16]  = {3,80,512, 3,80,512, 3,80,512,512, 3,80,512,512, 512,512};
  const int   kpads[16]  = {32,96,512, 32,96,512, 32,96,512,512, 32,96,512,512, 512,512};
  const int   cpads[16]  = {512,512,512, 512,512,512, 512,512,512,512, 512,512,512,512, 32,128};
  const int   nsrcs[16]  = {512,512,512, 512,512,512, 512,512,512,512, 512,512,512,512, 30,121};
  const long  offs[16]   = {W1X_J,W1W_J,W1H_J, W1X_K,W1W_K,W1H_K,
                            W2X_J,W2W_J,W2A_J,W2H_J, W2X_K,W2W_K,W2A_K,W2H_K, WWIN,WLIN};
  const void* srcs[16]   = {Wjx1,Wjx1,Wjh1, Wkx1,Wkx1,Wkh1,
                            Wjx2,Wjx2,Wjx2,Wjh2, Wkx2,Wkx2,Wkx2,Wkh2, Wwin,Wlin};
  const int Kpad = kpads[r], cp = cpads[r];
  const long tot = (long)Kpad * cp;
  if (e >= tot) return;
  const int j    = e & 7;
  const int lane = (e >> 3) & 63;
  const int rest = e >> 9;
  const int kbs  = Kpad >> 5;
  const int kb   = rest % kbs;
  const int slab = rest / kbs;
  const int col  = slab * 16 + (lane & 15);
  const int k    = kb * 32 + ((lane >> 4) << 3) + j;
  const int Klen = klens[r], row0 = row0s[r], N = nsrcs[r];
  bf16 v = (bf16)0.f;
  if (k < Klen && col < N) v = (bf16)ldIn(srcs[r], (long)(row0 + k) * N + col, isF32);
  W[offs[r] + e] = v;
}

// ---------------- shared MFMA helper ----------------
__device__ __forceinline__ void accum_term(f32x4& acc, int& cnt, int kh,
    const bf16* Arow, int astride, const bf16* B, int kbs,
    int lr, int ko, int lane) {
  for (int kb = 0; kb < kbs; ++kb) {
    if (((cnt++) & 1) != kh) continue;
    bf16x8 a = *(const bf16x8*)(Arow + (size_t)lr * astride + kb * 32 + ko);
    bf16x8 b = *(const bf16x8*)(B + ((size_t)kb * 64 + lane) * 8);
    acc = __builtin_amdgcn_mfma_f32_16x16x32_bf16(a, b, acc, 0, 0, 0);
  }
}

// padded acc store (20B stride, coprime with 32 banks)
__device__ __forceinline__ void accStore(float* d, const f32x4& a) {
  d[0] = a[0]; d[1] = a[1]; d[2] = a[2]; d[3] = a[3];
}

// ================= persistent scan kernel — 2 WG/CU, single-barrier pipeline =================
// 512 WGs: 16 m-groups x 8 batch rows, 32 col-slabs. LDS ~52KB -> 2 WGs/CU (TLP).
// __launch_bounds__(256, 2): 2nd arg = min waves/EU; for 256-thread blocks this
// equals WGs/CU — pins the register allocator to the occupancy the persistent
// group barrier REQUIRES (all 512 WGs co-resident; 1/CU would deadlock).
// iteration i: attention(i)+ff1(i+1) | ff2(i-1) | ff3(i-2) | out(i-3)
// A-fragments have 8 real rows; MFMA rows 8-15 duplicate rows 0-7 (outputs discarded).
__global__ __launch_bounds__(256, 2) void scan_kernel(KParams p) {
  const int isF32 = *p.flag;
  const int tid  = threadIdx.x;
  const int wid  = tid >> 6;
  const int lane = tid & 63;
  const int wg   = blockIdx.x;       // 512 WGs, 2 per CU
  const int m    = wg & 15;          // 16 m-groups; wg%8 -> XCD, so group stays on one XCD
  const int slab = wg >> 4;          // 32 col-slabs (16 cols each)
  const int m8   = m << 3;
  const int lr   = lane & 15;
  const int lra  = lr & 7;           // A-row (8 real rows; 8-15 duplicate)
  const int ko   = (lane >> 4) << 3;
  const int g    = wid >> 1;         // gate (0=j,1=k)
  const int kh   = wid & 1;          // K-half

  unsigned* hg1w = (unsigned*)p.h1;
  unsigned* hg2w = (unsigned*)p.h2;
  unsigned* hg3w = (unsigned*)p.h3;

  __shared__ alignas(16) bf16 h1L[NR * HSTRIDE];
  __shared__ alignas(16) bf16 h2L[NR * HSTRIDE];
  __shared__ alignas(16) bf16 h3L[NR * HSTRIDE];
  __shared__ alignas(16) bf16 xtR[4][NR][32];     // x ring: slots i-2..i+1
  __shared__ alignas(16) bf16 wR[3][NR][96];      // w ring: w(i), w(i-1), w(i-2)
  __shared__ float kapL[NR][NK];
  __shared__ float alphaL[NR][NK];
  __shared__ float betaL[NR][NK];
  __shared__ float phiL[NR][NU];
  __shared__ float accA[4][64][5];   // ff2 / window-out
  __shared__ float accB[4][64][5];   // kg, then ff1
  __shared__ float accC[4][64][5];   // ff3
  __shared__ bf16  hOut1[NR][16];
  __shared__ bf16  hOut2[NR][16];
  __shared__ bf16  hOut3[NR][16];

  for (int i = tid; i < 4 * NR * 32; i += 256) (&xtR[0][0][0])[i] = (bf16)0.f;
  for (int i = tid; i < 3 * NR * 96; i += 256) (&wR[0][0][0])[i] = (bf16)0.f;
  for (int i = tid; i < NR * NK; i += 256) (&kapL[0][0])[i] = 0.f;

  // per-thread weight bases (W2 A/H read from global/L2 — no LDS cache)
  const size_t oX2 = g ? W2X_K : W2X_J, oW2 = g ? W2W_K : W2W_J;
  const size_t oX1 = g ? W1X_K : W1X_J, oW1 = g ? W1W_K : W1W_J, oH1 = g ? W1H_K : W1H_J;
  const bf16* wA2 = p.W + (g ? W2A_K : W2A_J) + (size_t)slab * (16 * NS);
  const bf16* wH2 = p.W + (g ? W2H_K : W2H_J) + (size_t)slab * (16 * NS);

  // prologue: x(0) -> ring slot 0
  if (tid < 24) {
    int row = tid / 3, d = tid - row * 3;
    xtR[0][row][d] = (bf16)ldIn(p.x, ((long)(m8 + row) * NT + 0) * 3 + d, isF32);
  }
  __syncthreads();

  // ---- runtime XCD-locality detection ----
  int* gb = p.bar + m * 64;
  {
    int xcc = __builtin_amdgcn_s_getreg((3 << 11) | (0 << 6) | 20) & 31;  // HW_REG_XCC_ID
    if (tid == 0) {
      __hip_atomic_fetch_or((unsigned*)(gb + 32), 1u << xcc,
                            __ATOMIC_RELAXED, __HIP_MEMORY_SCOPE_AGENT);
      __threadfence();
      if ((__hip_atomic_fetch_add(gb + 16, 1, __ATOMIC_RELAXED, __HIP_MEMORY_SCOPE_AGENT) & 31) == 31)
        __hip_atomic_fetch_add(gb + 24, 1, __ATOMIC_RELAXED, __HIP_MEMORY_SCOPE_AGENT);
      while (__hip_atomic_load(gb + 24, __ATOMIC_RELAXED, __HIP_MEMORY_SCOPE_AGENT) < 1)
        __builtin_amdgcn_s_sleep(1);
    }
    __syncthreads();
  }
  const unsigned msk = __hip_atomic_load((unsigned*)(gb + 32),
                                         __ATOMIC_RELAXED, __HIP_MEMORY_SCOPE_AGENT);
  const bool fast = (msk & (msk - 1)) == 0;

  f32x4 acc2pre = {0.f, 0.f, 0.f, 0.f};   // ff2 pre-acc (x + h1A + w terms), carried over barrier
  int bt = 0;

  // ---- PROLOGUE: h1(0) = ff1([x(0), w(-1)=0], h1(-1)=0) -> publish parity 0 ----
  {
    f32x4 acc = {0.f, 0.f, 0.f, 0.f};
    int cnt = 0;
    accum_term(acc, cnt, kh, &xtR[0][0][0], 32, p.W + oX1 + (size_t)slab * NS,       1, lra, ko, lane);
    accum_term(acc, cnt, kh, &wR[0][0][0],  96, p.W + oW1 + (size_t)slab * (3 * NS), 3, lra, ko, lane);
    accStore(accB[wid][lane], acc);
    __syncthreads();
    {
      int ls = tid & 63, r = tid >> 6;
      if (ls < 32) {
        int s = (slab << 4) + (ls & 15);
        int rowIdx = ((ls >> 4) << 2) + r;   // 0..7
        float jp = accB[0][ls][r] + accB[1][ls][r] + p.bias[0 + s];
        float jj = 1.f / (1.f + __expf(-jp));
        hOut1[rowIdx][ls & 15] = (bf16)jj;   // j*(1-0) + (1-k)*0 = j
      }
    }
    __syncthreads();
    if (tid < 64) {
      int row = tid >> 3, c = tid & 7;
      union { unsigned u; unsigned short s[2]; } v;
      union { bf16 b; unsigned short s; } a0, a1;
      a0.b = hOut1[row][2 * c]; a1.b = hOut1[row][2 * c + 1];
      v.s[0] = a0.s; v.s[1] = a1.s;
      storeH(hg1w + (m8 + row) * 256 + slab * 8 + c, v.u, fast);   // parity 0
    }
    ++bt;
    group_arrive(gb);
    group_wait(gb, bt);
  }

  for (int i = 0; i <= NT + 2; ++i) {
    const bool A1  = (i <= NT - 1);            // attention(i), kg, h1 stage
    const bool AF1 = (i <= NT - 2);            // ff1 -> h1(i+1)
    const bool A2  = (i >= 1 && i <= NT);      // ff2 -> h2(i-1)
    const bool A3  = (i >= 2 && i <= NT + 1);  // ff3 -> h3(i-2)
    const bool AO  = (i >= 3) && (slab < 8);   // out rows (i-3)
    const bool APRE = (i <= NT - 1);           // ff2(i) pre-acc in barrier window

    // ---- P0: stage h1(i), h2(i-2), h3(i-3); load x(i+1); ONE drain ----
    if (i >= 1 && i <= NT + 1) {
      const bf16* g2 = p.h2 + (size_t)(i & 1) * HBUF + (size_t)m8 * NS;
      if (fast) stage_tile_async<AUX_SC0>(g2, h2L, tid);
      else      stage_tile_async<AUX_SC0S1>(g2, h2L, tid);
    }
    if (i >= 2) {
      const bf16* g3 = p.h3 + (size_t)((i + 1) & 1) * HBUF + (size_t)m8 * NS;
      if (fast) stage_tile_async<AUX_SC0>(g3, h3L, tid);
      else      stage_tile_async<AUX_SC0S1>(g3, h3L, tid);
    }
    if (A1) {
      const bf16* g1 = p.h1 + (size_t)(i & 1) * HBUF + (size_t)m8 * NS;
      if (fast) stage_tile_async<AUX_SC0>(g1, h1L, tid);
      else      stage_tile_async<AUX_SC0S1>(g1, h1L, tid);
    }
    if (i <= NT - 2 && tid < 24) {
      int row = tid / 3, d = tid - row * 3;
      xtR[(i + 1) & 3][row][d] = (bf16)ldIn(p.x, ((long)(m8 + row) * NT + (i + 1)) * 3 + d, isF32);
    }
    __syncthreads();   // drain all DMAs + x writes

    // ---- P1: mega-MFMA: ff2-finish -> accA, ff3 -> accC, kg -> accB ----
    if (A2) {
      f32x4 acc = acc2pre;
      int cnt = 20;
      accum_term(acc, cnt, kh, h2L, HSTRIDE, wH2, 16, lra, ko, lane);
      accStore(accA[wid][lane], acc);
    }
    if (A3) {
      f32x4 acc = {0.f, 0.f, 0.f, 0.f};
      int cnt = 0;
      accum_term(acc, cnt, kh, &xtR[(i - 2) & 3][0][0], 32, p.W + oX2 + (size_t)slab * NS,      1,  lra, ko, lane);
      accum_term(acc, cnt, kh, h2L, HSTRIDE, wA2, 16, lra, ko, lane);
      accum_term(acc, cnt, kh, &wR[(i - 2) % 3][0][0], 96, p.W + oW2 + (size_t)slab * (3 * NS), 3,  lra, ko, lane);
      accum_term(acc, cnt, kh, h3L, HSTRIDE, wH2, 16, lra, ko, lane);
      accStore(accC[wid][lane], acc);
    }
    if (A1) {
      int n2 = wid & 1, kh2 = wid >> 1;
      f32x4 acc = {0.f, 0.f, 0.f, 0.f};
      const bf16* B = p.W + WWIN + (size_t)n2 * (16 * NS);
      for (int kb = 0; kb < 16; ++kb) {
        if ((kb & 1) != kh2) continue;
        bf16x8 a = *(const bf16x8*)(h1L + (size_t)lra * HSTRIDE + kb * 32 + ko);
        bf16x8 b = *(const bf16x8*)(B + ((size_t)kb * 64 + lane) * 8);
        acc = __builtin_amdgcn_mfma_f32_16x16x32_bf16(a, b, acc, 0, 0, 0);
      }
      accStore(accB[wid][lane], acc);
    }
    __syncthreads();

    // ---- P2: ff2/ff3 epilogues + attn scalars (kg epilogue fused) ----
    const int arow = tid >> 4, aj = tid & 15;   // arow 0..15; rows 0..7 active
    int ulo, uhi;
    {
      int ls = tid & 63, r = tid >> 6;
      if (A2 && ls < 32) {
        int s = (slab << 4) + (ls & 15);
        int rowIdx = ((ls >> 4) << 2) + r;
        float jp = accA[0][ls][r] + accA[1][ls][r] + p.bias[1024 + s];
        float kp = accA[2][ls][r] + accA[3][ls][r] + p.bias[1536 + s];
        float ho = (float)h2L[rowIdx * HSTRIDE + s];
        float jj = 1.f / (1.f + __expf(-jp));
        float kk = 1.f / (1.f + __expf(-kp));
        hOut2[rowIdx][ls & 15] = (bf16)(jj * (1.f - ho) + (1.f - kk) * ho);
      }
      if (A3 && ls < 32) {
        int s = (slab << 4) + (ls & 15);
        int rowIdx = ((ls >> 4) << 2) + r;
        float jp = accC[0][ls][r] + accC[1][ls][r] + p.bias[1024 + s];
        float kp = accC[2][ls][r] + accC[3][ls][r] + p.bias[1536 + s];
        float ho = (float)h3L[rowIdx * HSTRIDE + s];
        float jj = 1.f / (1.f + __expf(-jp));
        float kk = 1.f / (1.f + __expf(-kp));
        hOut3[rowIdx][ls & 15] = (bf16)(jj * (1.f - ho) + (1.f - kk) * ho);
      }
      float lo = 1e30f, hi = -1e30f;
      if (A1 && arow < NR && aj < NK) {
        const int rr = arow & 3;
        const int lbase = (arow >> 2) << 4;
        const int o0 = aj, o1 = NK + aj, o2 = 2 * NK + aj;
        float ah    = accB[o0 >> 4][lbase | (o0 & 15)][rr] + accB[(o0 >> 4) + 2][lbase | (o0 & 15)][rr]
                    + ldIn(p.b_win, o0, isF32);
        float bepre = accB[o1 >> 4][lbase | (o1 & 15)][rr] + accB[(o1 >> 4) + 2][lbase | (o1 & 15)][rr]
                    + ldIn(p.b_win, o1, isF32);
        float dkpre = accB[o2 >> 4][lbase | (o2 & 15)][rr] + accB[(o2 >> 4) + 2][lbase | (o2 & 15)][rr]
                    + ldIn(p.b_win, o2, isF32);
        float be = expf(bepre);
        float dk = expf(dkpre);
        float al = expf(ah);
        float kap = kapL[arow][aj] + dk;
        kapL[arow][aj] = kap;
        alphaL[arow][aj] = al;
        betaL[arow][aj] = be;
        float arg = (ah + 18.42f) / be;
        if (arg > 0.f) { float R = sqrtf(arg); lo = kap - R; hi = kap + R; }
      }
      lo = fminf(lo, __shfl_xor(lo, 1));  hi = fmaxf(hi, __shfl_xor(hi, 1));
      lo = fminf(lo, __shfl_xor(lo, 2));  hi = fmaxf(hi, __shfl_xor(hi, 2));
      lo = fminf(lo, __shfl_xor(lo, 4));  hi = fmaxf(hi, __shfl_xor(hi, 4));
      lo = fminf(lo, __shfl_xor(lo, 8));  hi = fmaxf(hi, __shfl_xor(hi, 8));
      ulo = (lo <= 0.f) ? 0 : ((lo > 95.f) ? 96 : (int)floorf(lo));
      uhi = (hi >= 95.f) ? 95 : ((hi < 0.f) ? -1 : (int)ceilf(hi));
    }
    __syncthreads();   // kap/alpha/beta + hOut2/hOut3 visible

    // ---- P3: phi + publish h2(i-1) (tid<64) / h3(i-2) (tid 128..191) ----
    if (A1 && arow < NR) {
      for (int u = ulo + aj; u <= uhi; u += 16) {
        float s = 0.f, uf = (float)u;
        for (int k2 = 0; k2 < NK; ++k2) {
          float d = kapL[arow][k2] - uf;
          s += alphaL[arow][k2] * __expf(-betaL[arow][k2] * d * d);
        }
        phiL[arow][u] = s;
      }
    }
    if (A2 && tid < 64) {
      int row = tid >> 3, c = tid & 7;
      union { unsigned u; unsigned short s[2]; } v;
      union { bf16 b; unsigned short s; } a0, a1;
      a0.b = hOut2[row][2 * c]; a1.b = hOut2[row][2 * c + 1];
      v.s[0] = a0.s; v.s[1] = a1.s;
      storeH(hg2w + (size_t)((i - 1) & 1) * (HBUF / 2) + (m8 + row) * 256 + slab * 8 + c, v.u, fast);
    }
    if (A3 && tid >= 128 && tid < 192) {
      int t2 = tid - 128;
      int row = t2 >> 3, c = t2 & 7;
      union { unsigned u; unsigned short s[2]; } v;
      union { bf16 b; unsigned short s; } a0, a1;
      a0.b = hOut3[row][2 * c]; a1.b = hOut3[row][2 * c + 1];
      v.s[0] = a0.s; v.s[1] = a1.s;
      storeH(hg3w + (size_t)((i - 2) & 1) * (HBUF / 2) + (m8 + row) * 256 + slab * 8 + c, v.u, fast);
    }
    __syncthreads();   // phi visible

    // ---- P4: w(i) = phi @ c_vec ----
    if (A1 && arow < NR) {
      bf16* wOut = &wR[i % 3][0][0];
      if (isF32) {
        const float* cv = (const float*)p.c_vec + (long)(m8 + arow) * NU * NC;
        for (int ch = aj; ch < 20; ch += 16) {
          float a0 = 0.f, a1 = 0.f, a2 = 0.f, a3 = 0.f;
          for (int u = ulo; u <= uhi; ++u) {
            const float* q = cv + (long)u * NC + (ch << 2);
            float ph = phiL[arow][u];
            a0 += ph * q[0]; a1 += ph * q[1]; a2 += ph * q[2]; a3 += ph * q[3];
          }
          wOut[arow * 96 + (ch << 2) + 0] = (bf16)a0;
          wOut[arow * 96 + (ch << 2) + 1] = (bf16)a1;
          wOut[arow * 96 + (ch << 2) + 2] = (bf16)a2;
          wOut[arow * 96 + (ch << 2) + 3] = (bf16)a3;
        }
      } else {
        const long cv0 = (long)(m8 + arow) * NU * NC;
        for (int c = aj; c < NC; c += 16) {
          float acc = 0.f;
          for (int u = ulo; u <= uhi; ++u)
            acc += phiL[arow][u] * ldIn(p.c_vec, cv0 + (long)u * NC + c, isF32);
          wOut[arow * 96 + c] = (bf16)acc;
        }
      }
    }
    __syncthreads();   // w(i) visible

    // ---- P5: ff1(i+1) MFMA -> accB ----
    if (AF1) {
      f32x4 acc = {0.f, 0.f, 0.f, 0.f};
      int cnt = 0;
      accum_term(acc, cnt, kh, &xtR[(i + 1) & 3][0][0], 32, p.W + oX1 + (size_t)slab * NS,      1,  lra, ko, lane);
      accum_term(acc, cnt, kh, &wR[i % 3][0][0], 96, p.W + oW1 + (size_t)slab * (3 * NS),       3,  lra, ko, lane);
      accum_term(acc, cnt, kh, h1L, HSTRIDE, p.W + oH1 + (size_t)slab * (16 * NS), 16, lra, ko, lane);
      accStore(accB[wid][lane], acc);
    }
    __syncthreads();

    // ---- P6: ff1 epilogue -> hOut1 (h_old = h1(i)) ----
    if (AF1) {
      int ls = tid & 63, r = tid >> 6;
      if (ls < 32) {
        int s = (slab << 4) + (ls & 15);
        int rowIdx = ((ls >> 4) << 2) + r;
        float jp = accB[0][ls][r] + accB[1][ls][r] + p.bias[0 + s];
        float kp = accB[2][ls][r] + accB[3][ls][r] + p.bias[512 + s];
        float ho = (float)h1L[rowIdx * HSTRIDE + s];
        float jj = 1.f / (1.f + __expf(-jp));
        float kk = 1.f / (1.f + __expf(-kp));
        hOut1[rowIdx][ls & 15] = (bf16)(jj * (1.f - ho) + (1.f - kk) * ho);
      }
    }
    __syncthreads();

    // ---- P7: publish h1(i+1); barrier; window = ff2(i) pre-acc + out-head(i-3) ----
    if (AF1 && tid < 64) {
      int row = tid >> 3, c = tid & 7;
      union { unsigned u; unsigned short s[2]; } v;
      union { bf16 b; unsigned short s; } a0, a1;
      a0.b = hOut1[row][2 * c]; a1.b = hOut1[row][2 * c + 1];
      v.s[0] = a0.s; v.s[1] = a1.s;
      storeH(hg1w + (size_t)((i + 1) & 1) * (HBUF / 2) + (m8 + row) * 256 + slab * 8 + c, v.u, fast);
    }
    if (i < NT + 2) { ++bt; group_arrive(gb); }
    else            __syncthreads();
    if (APRE) {
      f32x4 a = {0.f, 0.f, 0.f, 0.f};
      int cnt = 0;
      accum_term(a, cnt, kh, &xtR[i & 3][0][0], 32, p.W + oX2 + (size_t)slab * NS,      1,  lra, ko, lane);
      accum_term(a, cnt, kh, h1L, HSTRIDE, wA2, 16, lra, ko, lane);
      accum_term(a, cnt, kh, &wR[i % 3][0][0], 96, p.W + oW2 + (size_t)slab * (3 * NS), 3,  lra, ko, lane);
      acc2pre = a;
    }
    if (AO) {   // out-head for rows (i-3), off the critical path (h3L = h3(i-3))
      f32x4 acc = {0.f, 0.f, 0.f, 0.f};
      const bf16* B = p.W + WLIN + (size_t)slab * (16 * NS);
      for (int kb = 0; kb < 16; ++kb) {
        if ((kb & 3) != wid) continue;
        bf16x8 a = *(const bf16x8*)(h3L + (size_t)lra * HSTRIDE + kb * 32 + ko);
        bf16x8 b = *(const bf16x8*)(B + ((size_t)kb * 64 + lane) * 8);
        acc = __builtin_amdgcn_mfma_f32_16x16x32_bf16(a, b, acc, 0, 0, 0);
      }
      accStore(accA[wid][lane], acc);
    }
    if (i >= 3 && slab < 8) {   // WG-uniform condition
      __syncthreads();
      if (tid < 32) {
        int o = (slab << 4) + (tid & 15);
        if (o < NOUT) {
          float bl = ldIn(p.b_lin, o, isF32);
          int rb = (tid >> 4) << 2;   // 0 or 4
          for (int r = 0; r < 4; ++r) {
            float v = accA[0][tid][r] + accA[1][tid][r] + accA[2][tid][r] + accA[3][tid][r] + bl;
            long oi = ((long)(m8 + rb + r) * NT + (i - 3)) * NOUT + o;
            if (isF32) ((float*)p.out)[oi] = v; else ((bf16*)p.out)[oi] = (bf16)v;
          }
        }
      }
    }
    if (i < NT + 2) group_wait(gb, bt);
  }
}

extern "C" void kernel_launch(void* const* d_in, const int* in_sizes, int n_in,
                              void* d_out, int out_size, void* d_ws, size_t ws_size,
                              hipStream_t stream) {
  (void)in_sizes; (void)n_in; (void)out_size; (void)ws_size;

  bf16*  wsW  = (bf16*)d_ws;
  float* bias = (float*)((char*)d_ws + BIAS_BYTE_OFF);
  bf16*  h1   = (bf16*)((char*)d_ws + H_BYTE_OFF);
  bf16*  h2   = h1 + 2 * HBUF;
  bf16*  h3   = h2 + 2 * HBUF;
  int*   flag = (int*)((char*)d_ws + FLAG_BYTE_OFF);
  int*   bar  = (int*)((char*)d_ws + BAR_BYTE_OFF);

  sniff_kernel<<<1, 256, 0, stream>>>((const unsigned short*)d_in[4], flag);

  prep_kernel<<<dim3(1024, 18), 256, 0, stream>>>(
      d_in[2], d_in[4], d_in[6], d_in[8], d_in[10], d_in[12], d_in[14], d_in[16],
      d_in[18], d_in[20],
      d_in[3], d_in[5], d_in[7], d_in[9], d_in[11], d_in[13], d_in[15], d_in[17],
      wsW, bias, h1, h2, h3, bar, flag);

  KParams kp;
  kp.x = d_in[0]; kp.c_vec = d_in[1]; kp.b_win = d_in[19]; kp.b_lin = d_in[21];
  kp.W = wsW; kp.bias = bias;
  kp.h1 = h1; kp.h2 = h2; kp.h3 = h3;
  kp.out = d_out;
  kp.flag = flag;
  kp.bar = bar;

  scan_kernel<<<512, 256, 0, stream>>>(kp);
}

// Round 11
// 9040.279 us; speedup vs baseline: 1.7448x; 1.7448x over previous
//
#include <hip/hip_runtime.h>
#include <hip/hip_bf16.h>

typedef __bf16 bf16;
typedef __bf16 bf16x8 __attribute__((ext_vector_type(8)));
typedef float  f32x4  __attribute__((ext_vector_type(4)));

#define AS1 __attribute__((address_space(1)))
#define AS3 __attribute__((address_space(3)))

#define NT   600
#define NB   128
#define NS   512
#define NU   96
#define NK   10
#define NC   80
#define NOUT 121

// packed-weight element offsets in ws (bf16 elements), layout [slab][kb][lane][8]
#define W1X_J 0
#define W1W_J 16384
#define W1H_J 65536
#define W1X_K 327680
#define W1W_K 344064
#define W1H_K 393216
#define W2X_J 655360
#define W2W_J 671744
#define W2A_J 720896
#define W2H_J 983040
#define W2X_K 1245184
#define W2W_K 1261568
#define W2A_K 1310720
#define W2H_K 1572864
#define WWIN  1835008
#define WLIN  1851392

#define BIAS_BYTE_OFF 3833856         // 2048 floats: [b1j|b1k|b2j|b2k]
#define H_BYTE_OFF    3842048         // h1[2][128][512], h2..., h3... bf16
#define HBUF 65536                    // bf16 elements per parity buffer
#define FLAG_BYTE_OFF 4659200         // int isF32
#define BAR_BYTE_OFF  4659264         // int bar[1024]; per group m*64: cnt@0 ep@8 dcnt@16 dep@24 xmask@32

#define HSTRIDE 520                   // LDS h-tile row stride in bf16 (1040B: 16B-aligned, bank skew)

// cache-policy aux for global_load_lds (gfx940+ CPol): SC0=bit0, SC1=bit4
#define AUX_SC0   1
#define AUX_SC0S1 17

template <bool B> struct BC { static constexpr bool value = B; };

__device__ __forceinline__ float ldIn(const void* q, long i, int isF32) {
  if (isF32) return ((const float*)q)[i];
  return (float)((const bf16*)q)[i];
}
template <bool F32>
__device__ __forceinline__ float ldInT(const void* q, long i) {
  if constexpr (F32) return ((const float*)q)[i];
  else               return (float)((const bf16*)q)[i];
}

struct KParams {
  const void* x;       // [128][600][3]
  const void* c_vec;   // [128][96][80]
  const void* b_win;   // [30]
  const void* b_lin;   // [121]
  const bf16* W;       // packed weights base
  const float* bias;   // [4*512]
  bf16* h1; bf16* h2; bf16* h3;  // [2][128][512] each
  void* out;           // [128*600][121]
  const int* flag;
  int* bar;
};

// ---- async global->LDS tile stage: 16 rows x 512 bf16, one 1KB DMA per row ----
template <int AUX>
__device__ __forceinline__ void stage_tile_async(const bf16* g, bf16* lds, int tid) {
  const int w = tid >> 6, lane = tid & 63;
#pragma unroll
  for (int r = 0; r < 4; ++r) {
    const int row = (w << 2) + r;
    __builtin_amdgcn_global_load_lds(
        (const AS1 void*)(g + (size_t)row * NS + (size_t)lane * 8),
        (AS3 void*)(lds + (size_t)row * HSTRIDE), 16, 0, AUX);
  }
}

// ---- central-counter group barrier (proven), split arrive/wait ----
__device__ __forceinline__ void group_arrive(int* gb) {
  __syncthreads();   // drains this WG's h stores before the arrive
  if (threadIdx.x == 0) {
    if ((__hip_atomic_fetch_add(gb, 1, __ATOMIC_RELAXED, __HIP_MEMORY_SCOPE_AGENT) & 31) == 31)
      __hip_atomic_fetch_add(gb + 8, 1, __ATOMIC_RELAXED, __HIP_MEMORY_SCOPE_AGENT);
  }
}
__device__ __forceinline__ void group_wait(int* gb, int target) {
  if (threadIdx.x == 0) {
    while (__hip_atomic_load(gb + 8, __ATOMIC_RELAXED, __HIP_MEMORY_SCOPE_AGENT) < target)
      __builtin_amdgcn_s_sleep(1);
  }
  __syncthreads();
  __atomic_signal_fence(__ATOMIC_ACQ_REL);
}

template <bool FAST>
__device__ __forceinline__ void storeHT(unsigned* dst, unsigned v) {
  if constexpr (FAST) *dst = v;   // plain store -> local L2 (same-XCD consumers read with sc0)
  else __hip_atomic_store(dst, v, __ATOMIC_RELAXED, __HIP_MEMORY_SCOPE_AGENT);
}

// ---------------- sniff: decide f32 vs bf16 input encoding ----------------
__global__ void sniff_kernel(const unsigned short* w, int* flag) {
  __shared__ int cnt;
  if (threadIdx.x == 0) cnt = 0;
  __syncthreads();
  int c = 0;
  for (int i = threadIdx.x; i < 8192; i += 256) {
    unsigned e = (w[2 * i] >> 7) & 0xFF;
    if (e == 0xFF || e < 96) c++;
  }
  atomicAdd(&cnt, c);
  __syncthreads();
  if (threadIdx.x == 0) *flag = (cnt > 512) ? 1 : 0;
}

// ---------------- prep: repack weights + zero state + zero barriers ----------------
__global__ void prep_kernel(const void* Wjx1, const void* Wjh1, const void* Wkx1, const void* Wkh1,
                            const void* Wjx2, const void* Wjh2, const void* Wkx2, const void* Wkh2,
                            const void* Wwin, const void* Wlin,
                            const void* bjx1, const void* bjh1, const void* bkx1, const void* bkh1,
                            const void* bjx2, const void* bjh2, const void* bkx2, const void* bkh2,
                            bf16* W, float* bias,
                            bf16* h1, bf16* h2, bf16* h3, int* bar,
                            const int* flag) {
  const int isF32 = *flag;
  const int r = blockIdx.y;
  const int e = blockIdx.x * 256 + threadIdx.x;
  if (r == 16) {
    if (e < 512) {
      bias[e]        = ldIn(bjx1, e, isF32) + ldIn(bjh1, e, isF32);
      bias[512 + e]  = ldIn(bkx1, e, isF32) + ldIn(bkh1, e, isF32);
      bias[1024 + e] = ldIn(bjx2, e, isF32) + ldIn(bjh2, e, isF32);
      bias[1536 + e] = ldIn(bkx2, e, isF32) + ldIn(bkh2, e, isF32);
    }
    return;
  }
  if (r == 17) {
    if (e < HBUF) {   // zero BOTH parities (pipelined schedule consumes zeros from each)
      h1[e] = (bf16)0.f; h1[HBUF + e] = (bf16)0.f;
      h2[e] = (bf16)0.f; h2[HBUF + e] = (bf16)0.f;
      h3[e] = (bf16)0.f; h3[HBUF + e] = (bf16)0.f;
    }
    if (e < 1024) bar[e] = 0;
    return;
  }
  const int   row0s[16]  = {0,3,0, 0,3,0, 0,515,3,0, 0,515,3,0, 0,0};
  const int   klens[16]  = {3,80,512, 3,80,512, 3,80,512,512, 3,80,512,512, 512,512};
  const int   kpads[16]  = {32,96,512, 32,96,512, 32,96,512,512, 32,96,512,512, 512,512};
  const int   cpads[16]  = {512,512,512, 512,512,512, 512,512,512,512, 512,512,512,512, 32,128};
  const int   nsrcs[16]  = {512,512,512, 512,512,512, 512,512,512,512, 512,512,512,512, 30,121};
  const long  offs[16]   = {W1X_J,W1W_J,W1H_J, W1X_K,W1W_K,W1H_K,
                            W2X_J,W2W_J,W2A_J,W2H_J, W2X_K,W2W_K,W2A_K,W2H_K, WWIN,WLIN};
  const void* srcs[16]   = {Wjx1,Wjx1,Wjh1, Wkx1,Wkx1,Wkh1,
                            Wjx2,Wjx2,Wjx2,Wjh2, Wkx2,Wkx2,Wkx2,Wkh2, Wwin,Wlin};
  const int Kpad = kpads[r], cp = cpads[r];
  const long tot = (long)Kpad * cp;
  if (e >= tot) return;
  const int j    = e & 7;
  const int lane = (e >> 3) & 63;
  const int rest = e >> 9;
  const int kbs  = Kpad >> 5;
  const int kb   = rest % kbs;
  const int slab = rest / kbs;
  const int col  = slab * 16 + (lane & 15);
  const int k    = kb * 32 + ((lane >> 4) << 3) + j;
  const int Klen = klens[r], row0 = row0s[r], N = nsrcs[r];
  bf16 v = (bf16)0.f;
  if (k < Klen && col < N) v = (bf16)ldIn(srcs[r], (long)(row0 + k) * N + col, isF32);
  W[offs[r] + e] = v;
}

// ---------------- shared MFMA helper (stride-2 form: no skipped-arm code) ----------------
// Equivalent to the proven parity-skip loop: takes kb with (cnt0+kb)&1 == kh,
// i.e. kb ≡ kh ^ (cnt0&1) (mod 2); advances cnt by kbs.
__device__ __forceinline__ void accum_term(f32x4& acc, int& cnt, int kh,
    const bf16* Arow, int astride, const bf16* B, int kbs,
    int lr, int ko, int lane) {
  for (int kb = (kh ^ (cnt & 1)) & 1; kb < kbs; kb += 2) {
    bf16x8 a = *(const bf16x8*)(Arow + (size_t)lr * astride + kb * 32 + ko);
    bf16x8 b = *(const bf16x8*)(B + ((size_t)kb * 64 + lane) * 8);
    acc = __builtin_amdgcn_mfma_f32_16x16x32_bf16(a, b, acc, 0, 0, 0);
  }
  cnt += kbs;
}

// padded acc store (20B stride, coprime with 32 banks)
__device__ __forceinline__ void accStore(float* d, const f32x4& a) {
  d[0] = a[0]; d[1] = a[1]; d[2] = a[2]; d[3] = a[3];
}

// ================= persistent scan kernel — single-barrier, 8-phase pipeline =================
// Round-8 schedule, specialized 4-way on (FAST, ISF32): each dynamic path is one
// contiguous code body (~1/4 the I-footprint) — I-cache capacity theory (R11).
__global__ __launch_bounds__(256) void scan_kernel(KParams p) {
  const int isF32 = *p.flag;
  const int tid  = threadIdx.x;
  const int wid  = tid >> 6;
  const int lane = tid & 63;
  const int wg   = blockIdx.x;       // 256 WGs, 1 per CU
  const int m    = wg & 7;           // 8 m-groups; round-robin maps a group onto one XCD
  const int slab = wg >> 3;          // 32 col-slabs (16 cols each)
  const int m16  = m << 4;
  const int lr   = lane & 15;
  const int ko   = (lane >> 4) << 3;
  const int g    = wid >> 1;         // gate (0=j,1=k)
  const int kh   = wid & 1;          // K-half

  unsigned* hg1w = (unsigned*)p.h1;
  unsigned* hg2w = (unsigned*)p.h2;
  unsigned* hg3w = (unsigned*)p.h3;

  __shared__ alignas(16) bf16 wLds[32768];        // W2 A_J|A_K|H_J|H_K, LDS-resident
  __shared__ alignas(16) bf16 h1L[16 * HSTRIDE];
  __shared__ alignas(16) bf16 h2L[16 * HSTRIDE];
  __shared__ alignas(16) bf16 h3L[16 * HSTRIDE];
  __shared__ alignas(16) bf16 xtR[4][16][32];     // x ring: slots i-2..i+1
  __shared__ alignas(16) bf16 wR[3][16][96];      // w ring: w(i), w(i-1), w(i-2)
  __shared__ float kapL[16][NK];
  __shared__ float alphaL[16][NK];
  __shared__ float betaL[16][NK];
  __shared__ float phiL[16][NU];
  __shared__ float accA[4][64][5];   // ff2 / window-out
  __shared__ float accB[4][64][5];   // kg, then ff1
  __shared__ float accC[4][64][5];   // ff3
  __shared__ bf16  hOut1[16][16];
  __shared__ bf16  hOut2[16][16];
  __shared__ bf16  hOut3[16][16];

  for (int i = tid; i < 4 * 16 * 32; i += 256) (&xtR[0][0][0])[i] = (bf16)0.f;
  for (int i = tid; i < 3 * 16 * 96; i += 256) (&wR[0][0][0])[i] = (bf16)0.f;
  for (int i = tid; i < 16 * NK; i += 256) (&kapL[0][0])[i] = 0.f;

  // per-thread weight bases
  const size_t oX2 = g ? W2X_K : W2X_J, oW2 = g ? W2W_K : W2W_J;
  const size_t oX1 = g ? W1X_K : W1X_J, oW1 = g ? W1W_K : W1W_J, oH1 = g ? W1H_K : W1H_J;
  const bf16* wA2 = wLds + (g ? 8192 : 0);
  const bf16* wH2 = wLds + (g ? 24576 : 16384);

  // one-time: DMA the 4 hot weight mats (this slab's slices) into LDS
  {
    const bf16* wsrc[4] = { p.W + W2A_J + (size_t)slab * (16 * NS),
                            p.W + W2A_K + (size_t)slab * (16 * NS),
                            p.W + W2H_J + (size_t)slab * (16 * NS),
                            p.W + W2H_K + (size_t)slab * (16 * NS) };
#pragma unroll
    for (int mt = 0; mt < 4; ++mt) {
#pragma unroll
      for (int r = 0; r < 4; ++r) {
        const int chunk = (wid << 2) + r;
        __builtin_amdgcn_global_load_lds(
            (const AS1 void*)(wsrc[mt] + chunk * 512 + lane * 8),
            (AS3 void*)(wLds + mt * 8192 + chunk * 512), 16, 0, 0);
      }
    }
  }
  // prologue: x(0) -> ring slot 0 (cold code; runtime isF32 fine)
  if (tid < 48) {
    int row = tid / 3, d = tid - row * 3;
    xtR[0][row][d] = (bf16)ldIn(p.x, ((long)(m16 + row) * NT + 0) * 3 + d, isF32);
  }
  __syncthreads();

  // ---- runtime XCD-locality detection ----
  int* gb = p.bar + m * 64;
  {
    int xcc = __builtin_amdgcn_s_getreg((3 << 11) | (0 << 6) | 20) & 31;  // HW_REG_XCC_ID
    if (tid == 0) {
      __hip_atomic_fetch_or((unsigned*)(gb + 32), 1u << xcc,
                            __ATOMIC_RELAXED, __HIP_MEMORY_SCOPE_AGENT);
      __threadfence();
      if ((__hip_atomic_fetch_add(gb + 16, 1, __ATOMIC_RELAXED, __HIP_MEMORY_SCOPE_AGENT) & 31) == 31)
        __hip_atomic_fetch_add(gb + 24, 1, __ATOMIC_RELAXED, __HIP_MEMORY_SCOPE_AGENT);
      while (__hip_atomic_load(gb + 24, __ATOMIC_RELAXED, __HIP_MEMORY_SCOPE_AGENT) < 1)
        __builtin_amdgcn_s_sleep(1);
    }
    __syncthreads();
  }
  const unsigned msk = __hip_atomic_load((unsigned*)(gb + 32),
                                         __ATOMIC_RELAXED, __HIP_MEMORY_SCOPE_AGENT);
  const bool fastDyn = (msk & (msk - 1)) == 0;

  // ================= specialized scan body =================
  auto body = [&](auto fc, auto ic) {
    constexpr bool FAST  = decltype(fc)::value;
    constexpr bool ISF32 = decltype(ic)::value;
    constexpr int  AUXH  = FAST ? AUX_SC0 : AUX_SC0S1;

    // hoisted per-thread constants (removes per-iteration global loads + branches)
    const int arow = tid >> 4, aj = tid & 15;
    float bw0 = 0.f, bw1 = 0.f, bw2 = 0.f;
    if (aj < NK) {
      bw0 = ldInT<ISF32>(p.b_win, aj);
      bw1 = ldInT<ISF32>(p.b_win, NK + aj);
      bw2 = ldInT<ISF32>(p.b_win, 2 * NK + aj);
    }
    float blin = 0.f;
    {
      int o = (slab << 4) + (tid & 15);
      if (slab < 8 && tid < 64 && o < NOUT) blin = ldInT<ISF32>(p.b_lin, o);
    }

    f32x4 acc2pre = {0.f, 0.f, 0.f, 0.f};   // ff2 pre-acc, carried over barrier
    int bt = 0;

    // ---- PROLOGUE: h1(0) = ff1([x(0), w(-1)=0], h1(-1)=0) -> publish parity 0 ----
    {
      f32x4 acc = {0.f, 0.f, 0.f, 0.f};
      int cnt = 0;
      accum_term(acc, cnt, kh, &xtR[0][0][0], 32, p.W + oX1 + (size_t)slab * NS,       1, lr, ko, lane);
      accum_term(acc, cnt, kh, &wR[0][0][0],  96, p.W + oW1 + (size_t)slab * (3 * NS), 3, lr, ko, lane);
      accStore(accB[wid][lane], acc);
      __syncthreads();
      {
        int ls = tid & 63, r = tid >> 6;
        int s = (slab << 4) + (ls & 15);
        int rowIdx = ((ls >> 4) << 2) + r;
        float jp = accB[0][ls][r] + accB[1][ls][r] + p.bias[0 + s];
        float jj = 1.f / (1.f + __expf(-jp));
        hOut1[rowIdx][ls & 15] = (bf16)jj;   // j*(1-0) + (1-k)*0 = j
      }
      __syncthreads();
      if (tid < 128) {
        int row = tid >> 3, c = tid & 7;
        union { unsigned u; unsigned short s[2]; } v;
        union { bf16 b; unsigned short s; } a0, a1;
        a0.b = hOut1[row][2 * c]; a1.b = hOut1[row][2 * c + 1];
        v.s[0] = a0.s; v.s[1] = a1.s;
        storeHT<FAST>(hg1w + (m16 + row) * 256 + slab * 8 + c, v.u);   // parity 0
      }
      ++bt;
      group_arrive(gb);
      group_wait(gb, bt);
    }

    for (int i = 0; i <= NT + 2; ++i) {
      const bool A1  = (i <= NT - 1);            // attention(i), kg, h1 stage
      const bool AF1 = (i <= NT - 2);            // ff1 -> h1(i+1)
      const bool A2  = (i >= 1 && i <= NT);      // ff2 -> h2(i-1)
      const bool A3  = (i >= 2 && i <= NT + 1);  // ff3 -> h3(i-2)
      const bool AO  = (i >= 3) && (slab < 8);   // out rows (i-3)
      const bool APRE = (i <= NT - 1);           // ff2(i) pre-acc in barrier window

      // ---- P0: stage h1(i), h2(i-2), h3(i-3); load x(i+1); ONE drain ----
      if (i >= 1 && i <= NT + 1)
        stage_tile_async<AUXH>(p.h2 + (size_t)(i & 1) * HBUF + (size_t)m16 * NS, h2L, tid);
      if (i >= 2)
        stage_tile_async<AUXH>(p.h3 + (size_t)((i + 1) & 1) * HBUF + (size_t)m16 * NS, h3L, tid);
      if (A1)
        stage_tile_async<AUXH>(p.h1 + (size_t)(i & 1) * HBUF + (size_t)m16 * NS, h1L, tid);
      if (i <= NT - 2 && tid < 48) {
        int row = tid / 3, d = tid - row * 3;
        xtR[(i + 1) & 3][row][d] = (bf16)ldInT<ISF32>(p.x, ((long)(m16 + row) * NT + (i + 1)) * 3 + d);
      }
      __syncthreads();   // drain all DMAs + x writes

      // ---- P1: mega-MFMA: ff2-finish -> accA, ff3 -> accC, kg -> accB ----
      if (A2) {
        f32x4 acc = acc2pre;
        int cnt = 20;
        accum_term(acc, cnt, kh, h2L, HSTRIDE, wH2, 16, lr, ko, lane);
        accStore(accA[wid][lane], acc);
      }
      if (A3) {
        f32x4 acc = {0.f, 0.f, 0.f, 0.f};
        int cnt = 0;
        accum_term(acc, cnt, kh, &xtR[(i - 2) & 3][0][0], 32, p.W + oX2 + (size_t)slab * NS,      1,  lr, ko, lane);
        accum_term(acc, cnt, kh, h2L, HSTRIDE, wA2, 16, lr, ko, lane);
        accum_term(acc, cnt, kh, &wR[(i - 2) % 3][0][0], 96, p.W + oW2 + (size_t)slab * (3 * NS), 3,  lr, ko, lane);
        accum_term(acc, cnt, kh, h3L, HSTRIDE, wH2, 16, lr, ko, lane);
        accStore(accC[wid][lane], acc);
      }
      if (A1) {
        int n2 = wid & 1, kh2 = wid >> 1;
        f32x4 acc = {0.f, 0.f, 0.f, 0.f};
        const bf16* B = p.W + WWIN + (size_t)n2 * (16 * NS);
        for (int kb = kh2; kb < 16; kb += 2) {
          bf16x8 a = *(const bf16x8*)(h1L + (size_t)lr * HSTRIDE + kb * 32 + ko);
          bf16x8 b = *(const bf16x8*)(B + ((size_t)kb * 64 + lane) * 8);
          acc = __builtin_amdgcn_mfma_f32_16x16x32_bf16(a, b, acc, 0, 0, 0);
        }
        accStore(accB[wid][lane], acc);
      }
      __syncthreads();

      // ---- P2: ff2/ff3 epilogues + attn scalars (kg epilogue fused) ----
      int ulo, uhi;
      {
        int ls = tid & 63, r = tid >> 6;
        if (A2) {
          int s = (slab << 4) + (ls & 15);
          int rowIdx = ((ls >> 4) << 2) + r;
          float jp = accA[0][ls][r] + accA[1][ls][r] + p.bias[1024 + s];
          float kp = accA[2][ls][r] + accA[3][ls][r] + p.bias[1536 + s];
          float ho = (float)h2L[rowIdx * HSTRIDE + s];
          float jj = 1.f / (1.f + __expf(-jp));
          float kk = 1.f / (1.f + __expf(-kp));
          hOut2[rowIdx][ls & 15] = (bf16)(jj * (1.f - ho) + (1.f - kk) * ho);
        }
        if (A3) {
          int s = (slab << 4) + (ls & 15);
          int rowIdx = ((ls >> 4) << 2) + r;
          float jp = accC[0][ls][r] + accC[1][ls][r] + p.bias[1024 + s];
          float kp = accC[2][ls][r] + accC[3][ls][r] + p.bias[1536 + s];
          float ho = (float)h3L[rowIdx * HSTRIDE + s];
          float jj = 1.f / (1.f + __expf(-jp));
          float kk = 1.f / (1.f + __expf(-kp));
          hOut3[rowIdx][ls & 15] = (bf16)(jj * (1.f - ho) + (1.f - kk) * ho);
        }
        float lo = 1e30f, hi = -1e30f;
        if (A1 && aj < NK) {
          const int rr = arow & 3;
          const int lbase = (arow >> 2) << 4;
          const int o0 = aj, o1 = NK + aj, o2 = 2 * NK + aj;
          float ah    = accB[o0 >> 4][lbase | (o0 & 15)][rr] + accB[(o0 >> 4) + 2][lbase | (o0 & 15)][rr] + bw0;
          float bepre = accB[o1 >> 4][lbase | (o1 & 15)][rr] + accB[(o1 >> 4) + 2][lbase | (o1 & 15)][rr] + bw1;
          float dkpre = accB[o2 >> 4][lbase | (o2 & 15)][rr] + accB[(o2 >> 4) + 2][lbase | (o2 & 15)][rr] + bw2;
          float be = expf(bepre);
          float dk = expf(dkpre);
          float al = expf(ah);
          float kap = kapL[arow][aj] + dk;
          kapL[arow][aj] = kap;
          alphaL[arow][aj] = al;
          betaL[arow][aj] = be;
          float arg = (ah + 18.42f) / be;
          if (arg > 0.f) { float R = sqrtf(arg); lo = kap - R; hi = kap + R; }
        }
        lo = fminf(lo, __shfl_xor(lo, 1));  hi = fmaxf(hi, __shfl_xor(hi, 1));
        lo = fminf(lo, __shfl_xor(lo, 2));  hi = fmaxf(hi, __shfl_xor(hi, 2));
        lo = fminf(lo, __shfl_xor(lo, 4));  hi = fmaxf(hi, __shfl_xor(hi, 4));
        lo = fminf(lo, __shfl_xor(lo, 8));  hi = fmaxf(hi, __shfl_xor(hi, 8));
        ulo = (lo <= 0.f) ? 0 : ((lo > 95.f) ? 96 : (int)floorf(lo));
        uhi = (hi >= 95.f) ? 95 : ((hi < 0.f) ? -1 : (int)ceilf(hi));
      }
      __syncthreads();   // kap/alpha/beta + hOut2/hOut3 visible

      // ---- P3: phi + publish h2(i-1) (tid<128) / h3(i-2) (tid>=128) ----
      if (A1) {
        for (int u = ulo + aj; u <= uhi; u += 16) {
          float s = 0.f, uf = (float)u;
          for (int k2 = 0; k2 < NK; ++k2) {
            float d = kapL[arow][k2] - uf;
            s += alphaL[arow][k2] * __expf(-betaL[arow][k2] * d * d);
          }
          phiL[arow][u] = s;
        }
      }
      if (A2 && tid < 128) {
        int row = tid >> 3, c = tid & 7;
        union { unsigned u; unsigned short s[2]; } v;
        union { bf16 b; unsigned short s; } a0, a1;
        a0.b = hOut2[row][2 * c]; a1.b = hOut2[row][2 * c + 1];
        v.s[0] = a0.s; v.s[1] = a1.s;
        storeHT<FAST>(hg2w + (size_t)((i - 1) & 1) * (HBUF / 2) + (m16 + row) * 256 + slab * 8 + c, v.u);
      }
      if (A3 && tid >= 128) {
        int t2 = tid - 128;
        int row = t2 >> 3, c = t2 & 7;
        union { unsigned u; unsigned short s[2]; } v;
        union { bf16 b; unsigned short s; } a0, a1;
        a0.b = hOut3[row][2 * c]; a1.b = hOut3[row][2 * c + 1];
        v.s[0] = a0.s; v.s[1] = a1.s;
        storeHT<FAST>(hg3w + (size_t)((i - 2) & 1) * (HBUF / 2) + (m16 + row) * 256 + slab * 8 + c, v.u);
      }
      __syncthreads();   // phi visible

      // ---- P4: w(i) = phi @ c_vec ----
      if (A1) {
        bf16* wOut = &wR[i % 3][0][0];
        if constexpr (ISF32) {
          const float* cv = (const float*)p.c_vec + (long)(m16 + arow) * NU * NC;
          for (int ch = aj; ch < 20; ch += 16) {
            float a0 = 0.f, a1 = 0.f, a2 = 0.f, a3 = 0.f;
            for (int u = ulo; u <= uhi; ++u) {
              const float* q = cv + (long)u * NC + (ch << 2);
              float ph = phiL[arow][u];
              a0 += ph * q[0]; a1 += ph * q[1]; a2 += ph * q[2]; a3 += ph * q[3];
            }
            wOut[arow * 96 + (ch << 2) + 0] = (bf16)a0;
            wOut[arow * 96 + (ch << 2) + 1] = (bf16)a1;
            wOut[arow * 96 + (ch << 2) + 2] = (bf16)a2;
            wOut[arow * 96 + (ch << 2) + 3] = (bf16)a3;
          }
        } else {
          const long cv0 = (long)(m16 + arow) * NU * NC;
          for (int c = aj; c < NC; c += 16) {
            float acc = 0.f;
            for (int u = ulo; u <= uhi; ++u)
              acc += phiL[arow][u] * ldInT<ISF32>(p.c_vec, cv0 + (long)u * NC + c);
            wOut[arow * 96 + c] = (bf16)acc;
          }
        }
      }
      __syncthreads();   // w(i) visible

      // ---- P5: ff1(i+1) MFMA -> accB ----
      if (AF1) {
        f32x4 acc = {0.f, 0.f, 0.f, 0.f};
        int cnt = 0;
        accum_term(acc, cnt, kh, &xtR[(i + 1) & 3][0][0], 32, p.W + oX1 + (size_t)slab * NS,      1,  lr, ko, lane);
        accum_term(acc, cnt, kh, &wR[i % 3][0][0], 96, p.W + oW1 + (size_t)slab * (3 * NS),       3,  lr, ko, lane);
        accum_term(acc, cnt, kh, h1L, HSTRIDE, p.W + oH1 + (size_t)slab * (16 * NS), 16, lr, ko, lane);
        accStore(accB[wid][lane], acc);
      }
      __syncthreads();

      // ---- P6: ff1 epilogue -> hOut1 (h_old = h1(i)) ----
      if (AF1) {
        int ls = tid & 63, r = tid >> 6;
        int s = (slab << 4) + (ls & 15);
        int rowIdx = ((ls >> 4) << 2) + r;
        float jp = accB[0][ls][r] + accB[1][ls][r] + p.bias[0 + s];
        float kp = accB[2][ls][r] + accB[3][ls][r] + p.bias[512 + s];
        float ho = (float)h1L[rowIdx * HSTRIDE + s];
        float jj = 1.f / (1.f + __expf(-jp));
        float kk = 1.f / (1.f + __expf(-kp));
        hOut1[rowIdx][ls & 15] = (bf16)(jj * (1.f - ho) + (1.f - kk) * ho);
      }
      __syncthreads();

      // ---- P7: publish h1(i+1); barrier; window = ff2(i) pre-acc + out-head(i-3) ----
      if (AF1 && tid < 128) {
        int row = tid >> 3, c = tid & 7;
        union { unsigned u; unsigned short s[2]; } v;
        union { bf16 b; unsigned short s; } a0, a1;
        a0.b = hOut1[row][2 * c]; a1.b = hOut1[row][2 * c + 1];
        v.s[0] = a0.s; v.s[1] = a1.s;
        storeHT<FAST>(hg1w + (size_t)((i + 1) & 1) * (HBUF / 2) + (m16 + row) * 256 + slab * 8 + c, v.u);
      }
      if (i < NT + 2) { ++bt; group_arrive(gb); }
      else            __syncthreads();
      if (APRE) {
        f32x4 a = {0.f, 0.f, 0.f, 0.f};
        int cnt = 0;
        accum_term(a, cnt, kh, &xtR[i & 3][0][0], 32, p.W + oX2 + (size_t)slab * NS,      1,  lr, ko, lane);
        accum_term(a, cnt, kh, h1L, HSTRIDE, wA2, 16, lr, ko, lane);
        accum_term(a, cnt, kh, &wR[i % 3][0][0], 96, p.W + oW2 + (size_t)slab * (3 * NS), 3,  lr, ko, lane);
        acc2pre = a;
      }
      if (AO) {   // out-head for rows (i-3), off the critical path (h3L = h3(i-3))
        f32x4 acc = {0.f, 0.f, 0.f, 0.f};
        const bf16* B = p.W + WLIN + (size_t)slab * (16 * NS);
        for (int kb = wid; kb < 16; kb += 4) {
          bf16x8 a = *(const bf16x8*)(h3L + (size_t)lr * HSTRIDE + kb * 32 + ko);
          bf16x8 b = *(const bf16x8*)(B + ((size_t)kb * 64 + lane) * 8);
          acc = __builtin_amdgcn_mfma_f32_16x16x32_bf16(a, b, acc, 0, 0, 0);
        }
        accStore(accA[wid][lane], acc);
      }
      if (i >= 3 && slab < 8) {   // WG-uniform condition
        __syncthreads();
        if (tid < 64) {
          int o = (slab << 4) + (tid & 15);
          if (o < NOUT) {
            int rb = (tid >> 4) << 2;
            for (int r = 0; r < 4; ++r) {
              float v = accA[0][tid][r] + accA[1][tid][r] + accA[2][tid][r] + accA[3][tid][r] + blin;
              long oi = ((long)(m16 + rb + r) * NT + (i - 3)) * NOUT + o;
              if constexpr (ISF32) ((float*)p.out)[oi] = v; else ((bf16*)p.out)[oi] = (bf16)v;
            }
          }
        }
      }
      if (i < NT + 2) group_wait(gb, bt);
    }
  };

  if (fastDyn) { if (isF32) body(BC<true>{},  BC<true>{});  else body(BC<true>{},  BC<false>{}); }
  else         { if (isF32) body(BC<false>{}, BC<true>{});  else body(BC<false>{}, BC<false>{}); }
}

extern "C" void kernel_launch(void* const* d_in, const int* in_sizes, int n_in,
                              void* d_out, int out_size, void* d_ws, size_t ws_size,
                              hipStream_t stream) {
  (void)in_sizes; (void)n_in; (void)out_size; (void)ws_size;

  bf16*  wsW  = (bf16*)d_ws;
  float* bias = (float*)((char*)d_ws + BIAS_BYTE_OFF);
  bf16*  h1   = (bf16*)((char*)d_ws + H_BYTE_OFF);
  bf16*  h2   = h1 + 2 * HBUF;
  bf16*  h3   = h2 + 2 * HBUF;
  int*   flag = (int*)((char*)d_ws + FLAG_BYTE_OFF);
  int*   bar  = (int*)((char*)d_ws + BAR_BYTE_OFF);

  sniff_kernel<<<1, 256, 0, stream>>>((const unsigned short*)d_in[4], flag);

  prep_kernel<<<dim3(1024, 18), 256, 0, stream>>>(
      d_in[2], d_in[4], d_in[6], d_in[8], d_in[10], d_in[12], d_in[14], d_in[16],
      d_in[18], d_in[20],
      d_in[3], d_in[5], d_in[7], d_in[9], d_in[11], d_in[13], d_in[15], d_in[17],
      wsW, bias, h1, h2, h3, bar, flag);

  KParams kp;
  kp.x = d_in[0]; kp.c_vec = d_in[1]; kp.b_win = d_in[19]; kp.b_lin = d_in[21];
  kp.W = wsW; kp.bias = bias;
  kp.h1 = h1; kp.h2 = h2; kp.h3 = h3;
  kp.out = d_out;
  kp.flag = flag;
  kp.bar = bar;

  scan_kernel<<<256, 256, 0, stream>>>(kp);
}